// Round 3
// baseline (10531.357 us; speedup 1.0000x reference)
//
#include <hip/hip_runtime.h>

// Problem constants
#define BATCH 8
#define T 4096
#define NCH 256
#define NCTX 80
#define NLAYERS 8

typedef unsigned short u16;

__device__ __forceinline__ float b2f(u16 u) {
    unsigned v = ((unsigned)u) << 16;
    float f;
    __builtin_memcpy(&f, &v, 4);
    return f;
}
__device__ __forceinline__ u16 f2b(float f) {
    unsigned v;
    __builtin_memcpy(&v, &f, 4);
    unsigned r = v + 0x7FFFu + ((v >> 16) & 1u);
    return (u16)(r >> 16);
}

// Load an INPUT element in either dtype mode.
template <bool F32>
__device__ __forceinline__ float LD(const void* p, size_t i) {
    if constexpr (F32) {
        return ((const float*)p)[i];
    } else {
        return b2f(((const u16*)p)[i]);
    }
}

// Active-variant gate: flag==0 -> fp32 inputs, flag==1 -> bf16 inputs.
template <bool F32>
__device__ __forceinline__ bool skip(const int* flag) {
    int f = *flag;
    if constexpr (F32) return f != 0;
    else return f == 0;
}

// ---------------- dtype probe ----------------
// For bf16 data, even halfwords are bf16 values of N(0,1) draws -> exponent
// field in a sane range ~always. For fp32 data, even halfwords are low
// mantissa bits -> exponent field uniform -> ~21% sane. Threshold at 50%.
__global__ void probe_kernel(const u16* __restrict__ fc, int* __restrict__ flag) {
    __shared__ int cnt;
    if (threadIdx.x == 0) cnt = 0;
    __syncthreads();
    int local = 0;
#pragma unroll
    for (int j = 0; j < 16; j++) {
        u16 u = fc[2 * (threadIdx.x * 16 + j)];
        int e = (u >> 7) & 0xFF;
        if (e >= 0x50 && e <= 0x85) local++;
    }
    atomicAdd(&cnt, local);
    __syncthreads();
    if (threadIdx.x == 0) *flag = (cnt >= 2048) ? 1 : 0;  // 1 = bf16 inputs
}

// ---------------- start conv (4 -> 256, 1x1) + zero out_acc ----------------
template <bool F32>
__global__ void start_kernel(const void* __restrict__ fc, const void* __restrict__ w,
                             const void* __restrict__ bias, u16* __restrict__ x,
                             u16* __restrict__ oacc, const int* __restrict__ flag) {
    if (skip<F32>(flag)) return;
    int i = blockIdx.x * 256 + threadIdx.x;   // covers 8*256*4096
    int t = i & 4095;
    int c = (i >> 12) & 255;
    int b = i >> 20;
    c = __builtin_amdgcn_readfirstlane(c);    // uniform per block (256 | 4096)
    float acc = LD<F32>(bias, c);
    size_t f0 = (size_t)b * 8 * T + t;
#pragma unroll
    for (int k = 0; k < 4; k++) acc += LD<F32>(w, c * 4 + k) * LD<F32>(fc, f0 + k * T);
    x[i] = f2b(acc);
    oacc[i] = 0;   // bf16 zero
}

// ---------------- layer kernel A: dilated conv + cond + gated activation ----------------
// block (64,4); grid (T/64, 16, B). Each block: 16 tanh-rows + 16 sigmoid-rows x 64 t.
template <bool F32>
__global__ __launch_bounds__(256) void layer_a_kernel(
    const u16* __restrict__ x, const void* __restrict__ w_in, const void* __restrict__ b_in,
    const void* __restrict__ w_cond, const void* __restrict__ b_cond,
    const void* __restrict__ ctx, u16* __restrict__ acts, int layer, int dil,
    const int* __restrict__ flag) {
    if (skip<F32>(flag)) return;
    const int tx = threadIdx.x, ty = threadIdx.y;
    const int t0 = blockIdx.x * 64, t = t0 + tx;
    const int cp = blockIdx.y, b = blockIdx.z;

    int rb = (ty < 2) ? (cp * 16 + ty * 8) : (256 + cp * 16 + (ty - 2) * 8);
    rb = __builtin_amdgcn_readfirstlane(rb);
    const int orow = layer * 512 + rb;

    float acc[8];
#pragma unroll
    for (int r = 0; r < 8; r++) acc[r] = LD<F32>(b_in, orow + r) + LD<F32>(b_cond, orow + r);

    const u16* xb = x + (size_t)b * NCH * T + t;
    const bool okm = (t - dil) >= 0;
    const bool okp = (t + dil) < T;
    const size_t wbase = (size_t)orow * (NCH * 3);

    for (int c = 0; c < NCH; c++) {
        float xm = okm ? b2f(xb[c * T - dil]) : 0.f;
        float x0 = b2f(xb[c * T]);
        float xp = okp ? b2f(xb[c * T + dil]) : 0.f;
        const size_t wr = wbase + c * 3;
#pragma unroll
        for (int r = 0; r < 8; r++) {
            acc[r] += LD<F32>(w_in, wr + r * 768) * xm + LD<F32>(w_in, wr + r * 768 + 1) * x0 +
                      LD<F32>(w_in, wr + r * 768 + 2) * xp;
        }
    }

    // conditioning: + cond_w[orow, j] * context[b, j, t]
    const size_t cb = (size_t)b * NCTX * T + t;
    const size_t wc = (size_t)orow * NCTX;
    for (int j = 0; j < NCTX; j++) {
        float cv = LD<F32>(ctx, cb + (size_t)j * T);
#pragma unroll
        for (int r = 0; r < 8; r++) acc[r] += LD<F32>(w_cond, wc + r * NCTX + j) * cv;
    }

    // exchange via LDS to pair tanh/sigmoid halves
    __shared__ float a_sm[32][64];
#pragma unroll
    for (int r = 0; r < 8; r++) a_sm[ty * 8 + r][tx] = acc[r];
    __syncthreads();

    u16* ab = acts + (size_t)b * NCH * T + (size_t)cp * 16 * T + t0;
#pragma unroll
    for (int m = 0; m < 4; m++) {
        int rl = m * 4 + ty;  // 0..15
        float lo = a_sm[rl][tx];
        float hi = a_sm[16 + rl][tx];
        float e2 = __expf(2.f * lo);
        float th = 1.f - 2.f / (e2 + 1.f);     // tanh, safe at +/-inf
        float sg = 1.f / (1.f + __expf(-hi));  // sigmoid
        ab[(size_t)rl * T + tx] = f2b(th * sg);
    }
}

// ---------------- layer kernel B: 1x1 rs conv, update x and out_acc ----------------
// block (64,4); grid (T/64, last?8:16, B)
template <bool F32>
__global__ __launch_bounds__(256) void layer_b_kernel(
    const u16* __restrict__ acts, const void* __restrict__ w_rs,
    const void* __restrict__ b_rs, u16* __restrict__ x, u16* __restrict__ oacc,
    int layer, int last, const int* __restrict__ flag) {
    if (skip<F32>(flag)) return;
    const int tx = threadIdx.x, ty = threadIdx.y;
    const int t = blockIdx.x * 64 + tx;
    const int b = blockIdx.z;
    int rb = blockIdx.y * 32 + ty * 8;
    rb = __builtin_amdgcn_readfirstlane(rb);
    const int orow = layer * 512 + rb;

    float acc[8];
#pragma unroll
    for (int r = 0; r < 8; r++) acc[r] = LD<F32>(b_rs, orow + r);

    const u16* ab = acts + (size_t)b * NCH * T + t;
    const size_t wbase = (size_t)orow * NCH;
    for (int c = 0; c < NCH; c++) {
        float av = b2f(ab[c * T]);
#pragma unroll
        for (int r = 0; r < 8; r++) acc[r] += LD<F32>(w_rs, wbase + c + r * NCH) * av;
    }

    if (last) {
        u16* p = oacc + ((size_t)b * NCH + rb) * T + t;
#pragma unroll
        for (int r = 0; r < 8; r++) p[r * T] = f2b(b2f(p[r * T]) + acc[r]);
    } else if (rb < 256) {
        u16* p = x + ((size_t)b * NCH + rb) * T + t;
#pragma unroll
        for (int r = 0; r < 8; r++) p[r * T] = f2b(b2f(p[r * T]) + acc[r]);
    } else {
        u16* p = oacc + ((size_t)b * NCH + (rb - 256)) * T + t;
#pragma unroll
        for (int r = 0; r < 8; r++) p[r * T] = f2b(b2f(p[r * T]) + acc[r]);
    }
}

// ---------------- end conv (256 -> 8) + affine + output assembly ----------------
template <bool F32>
__global__ void end_kernel(const u16* __restrict__ oacc, const void* __restrict__ w_end,
                           const void* __restrict__ b_end, const void* __restrict__ fc,
                           void* __restrict__ out, const int* __restrict__ flag) {
    if (skip<F32>(flag)) return;
    int i = blockIdx.x * 256 + threadIdx.x;  // 8*4096
    int t = i & 4095;
    int b = i >> 12;
    float o8[8];
#pragma unroll
    for (int o = 0; o < 8; o++) o8[o] = LD<F32>(b_end, o);
    const u16* ob = oacc + (size_t)b * NCH * T + t;
    for (int c = 0; c < NCH; c++) {
        float v = b2f(ob[c * T]);
#pragma unroll
        for (int o = 0; o < 8; o++) o8[o] += LD<F32>(w_end, o * NCH + c) * v;
    }
    size_t y0 = (size_t)b * 8 * T + t;                          // concat(f0,f1')
    size_t y1 = (size_t)BATCH * 8 * T + (size_t)b * 4 * T + t;  // log_s
    size_t f = (size_t)b * 8 * T + t;
#pragma unroll
    for (int j = 0; j < 4; j++) {
        float f1 = LD<F32>(fc, f + (4 + j) * T);
        float ls = o8[4 + j];
        float val = expf(ls) * f1 + o8[j];
        if constexpr (F32) {
            float* o = (float*)out;
            o[y0 + j * T] = ((const float*)fc)[f + j * T];  // f0 bit-exact
            o[y0 + (4 + j) * T] = val;
            o[y1 + j * T] = ls;
        } else {
            u16* o = (u16*)out;
            o[y0 + j * T] = ((const u16*)fc)[f + j * T];    // f0 bit-exact
            o[y0 + (4 + j) * T] = f2b(val);
            o[y1 + j * T] = f2b(ls);
        }
    }
}

template <bool F32>
static void launch_net(const void* forecast, const void* context, const void* start_w,
                       const void* start_b, const void* cond_w, const void* cond_b,
                       const void* in_w, const void* in_b, const void* rs_w,
                       const void* rs_b, const void* end_w, const void* end_b,
                       void* out, u16* xbuf, u16* oacc, u16* acts, const int* flag,
                       hipStream_t stream) {
    start_kernel<F32><<<(BATCH * NCH * T) / 256, 256, 0, stream>>>(
        forecast, start_w, start_b, xbuf, oacc, flag);
    const int dil[NLAYERS] = {1, 2, 4, 8, 16, 32, 64, 128};
    for (int l = 0; l < NLAYERS; l++) {
        layer_a_kernel<F32><<<dim3(T / 64, 16, BATCH), dim3(64, 4), 0, stream>>>(
            xbuf, in_w, in_b, cond_w, cond_b, context, acts, l, dil[l], flag);
        int last = (l == NLAYERS - 1);
        layer_b_kernel<F32><<<dim3(T / 64, last ? 8 : 16, BATCH), dim3(64, 4), 0, stream>>>(
            acts, rs_w, rs_b, xbuf, oacc, l, last, flag);
    }
    end_kernel<F32><<<(BATCH * T) / 256, 256, 0, stream>>>(
        oacc, end_w, end_b, forecast, out, flag);
}

extern "C" void kernel_launch(void* const* d_in, const int* in_sizes, int n_in,
                              void* d_out, int out_size, void* d_ws, size_t ws_size,
                              hipStream_t stream) {
    const void* forecast = d_in[0];
    const void* context  = d_in[1];
    const void* start_w  = d_in[2];
    const void* start_b  = d_in[3];
    const void* cond_w   = d_in[4];
    const void* cond_b   = d_in[5];
    const void* in_w     = d_in[6];
    const void* in_b     = d_in[7];
    const void* rs_w     = d_in[8];
    const void* rs_b     = d_in[9];
    const void* end_w    = d_in[10];
    const void* end_b    = d_in[11];

    // Workspace: flag (256 B header) + 3 x 16 MiB bf16 buffers.
    char* W = (char*)d_ws;
    int* flag = (int*)(W + 0);
    u16* xbuf = (u16*)(W + 256);
    u16* oacc = (u16*)(W + 256 + 16777216);
    u16* acts = (u16*)(W + 256 + 33554432);

    probe_kernel<<<1, 256, 0, stream>>>((const u16*)forecast, flag);

    launch_net<false>(forecast, context, start_w, start_b, cond_w, cond_b, in_w, in_b,
                      rs_w, rs_b, end_w, end_b, d_out, xbuf, oacc, acts, flag, stream);
    launch_net<true>(forecast, context, start_w, start_b, cond_w, cond_b, in_w, in_b,
                     rs_w, rs_b, end_w, end_b, d_out, xbuf, oacc, acts, flag, stream);
}

// Round 4
// 923.903 us; speedup vs baseline: 11.3988x; 11.3988x over previous
//
#include <hip/hip_runtime.h>

#define BATCH 8
#define T 4096
#define NCH 256
#define NCTX 80
#define NLAYERS 8

typedef unsigned short u16;
typedef __attribute__((ext_vector_type(8))) short short8;
typedef __attribute__((ext_vector_type(4))) float float4v;

__device__ __forceinline__ float b2f(u16 u) {
    unsigned v = ((unsigned)u) << 16;
    float f;
    __builtin_memcpy(&f, &v, 4);
    return f;
}
__device__ __forceinline__ u16 f2b(float f) {
    unsigned v;
    __builtin_memcpy(&v, &f, 4);
    unsigned r = v + 0x7FFFu + ((v >> 16) & 1u);
    return (u16)(r >> 16);
}

template <bool F32>
__device__ __forceinline__ float LD(const void* p, size_t i) {
    if constexpr (F32) return ((const float*)p)[i];
    else return b2f(((const u16*)p)[i]);
}
template <bool F32>
__device__ __forceinline__ bool skipv(const int* flag) {
    int f = *flag;
    return F32 ? (f != 0) : (f == 0);
}

// ---------------- dtype probe (same logic that passed round 3) ----------------
__global__ void probe_kernel(const u16* __restrict__ fc, int* __restrict__ flag) {
    __shared__ int cnt;
    if (threadIdx.x == 0) cnt = 0;
    __syncthreads();
    int local = 0;
#pragma unroll
    for (int j = 0; j < 16; j++) {
        u16 u = fc[2 * (threadIdx.x * 16 + j)];
        int e = (u >> 7) & 0xFF;
        if (e >= 0x50 && e <= 0x85) local++;
    }
    atomicAdd(&cnt, local);
    __syncthreads();
    if (threadIdx.x == 0) *flag = (cnt >= 2048) ? 1 : 0;  // 1 = bf16 inputs
}

// ---------------- generic convert to bf16 ----------------
template <bool F32>
__global__ void cvt_kernel(const void* __restrict__ src, u16* __restrict__ dst, int n,
                           const int* __restrict__ flag) {
    if (skipv<F32>(flag)) return;
    int i = blockIdx.x * 256 + threadIdx.x;
    if (i < n) dst[i] = f2b(LD<F32>(src, i));
}

// ---------------- build Wc [8][512][864]: 3 taps + cond + bias col + pad ----------------
template <bool F32>
__global__ void prep_wc(const void* __restrict__ in_w, const void* __restrict__ in_b,
                        const void* __restrict__ cond_w, const void* __restrict__ cond_b,
                        u16* __restrict__ Wc, const int* __restrict__ flag) {
    if (skipv<F32>(flag)) return;
    int row = blockIdx.x;  // 0..4095 = l*512+o
    for (int it = 0; it < 4; it++) {
        int col = it * 256 + threadIdx.x;
        if (col >= 864) break;
        float v;
        if (col < 256)       v = LD<F32>(in_w, ((size_t)row * 256 + col) * 3);
        else if (col < 512)  v = LD<F32>(in_w, ((size_t)row * 256 + (col - 256)) * 3 + 1);
        else if (col < 768)  v = LD<F32>(in_w, ((size_t)row * 256 + (col - 512)) * 3 + 2);
        else if (col < 848)  v = LD<F32>(cond_w, (size_t)row * 80 + (col - 768));
        else if (col == 848) v = LD<F32>(in_b, row) + LD<F32>(cond_b, row);
        else                 v = 0.f;
        Wc[(size_t)row * 864 + col] = f2b(v);
    }
}

// ---------------- transpose context -> ctx_t [B][T][96] (col80=1.0 bias, 81..95=0) --------
template <bool F32>
__global__ void prep_ctx(const void* __restrict__ ctx, u16* __restrict__ ctxt,
                         const int* __restrict__ flag) {
    if (skipv<F32>(flag)) return;
    __shared__ float sm[80][65];
    const int tid = threadIdx.x;
    const int b = blockIdx.y, t0 = blockIdx.x * 64;
    for (int it = 0; it < 20; it++) {
        int e = it * 256 + tid;
        int j = e >> 6, tt = e & 63;
        sm[j][tt] = LD<F32>(ctx, ((size_t)b * 80 + j) * T + t0 + tt);
    }
    __syncthreads();
    for (int it = 0; it < 24; it++) {
        int e = it * 256 + tid;
        int r = e / 96, c = e - r * 96;
        float v = (c < 80) ? sm[c][r] : (c == 80 ? 1.f : 0.f);
        ctxt[((size_t)b * T + t0 + r) * 96 + c] = f2b(v);
    }
}

// ---------------- start conv (4 -> 256, 1x1) -> x_t [B][T][256] ----------------
template <bool F32>
__global__ void start_kernel(const void* __restrict__ fc, const void* __restrict__ w,
                             const void* __restrict__ bias, u16* __restrict__ xt,
                             const int* __restrict__ flag) {
    if (skipv<F32>(flag)) return;
    __shared__ float fsm[4][64];
    __shared__ float wsm[1024];
    __shared__ float bsm[256];
    const int tid = threadIdx.x;
    const int b = blockIdx.y, t0 = blockIdx.x * 64;
    fsm[tid >> 6][tid & 63] = LD<F32>(fc, ((size_t)b * 8 + (tid >> 6)) * T + t0 + (tid & 63));
    for (int it = 0; it < 4; it++) wsm[it * 256 + tid] = LD<F32>(w, it * 256 + tid);
    bsm[tid] = LD<F32>(bias, tid);
    __syncthreads();
    for (int r = 0; r < 64; r++) {
        int c = tid;
        float a = bsm[c];
#pragma unroll
        for (int k = 0; k < 4; k++) a += wsm[c * 4 + k] * fsm[k][r];
        xt[((size_t)b * T + t0 + r) * 256 + c] = f2b(a);
    }
}

// ---------------- fused WaveNet layer: dilated conv GEMM + gate + rs GEMM ----------------
// grid (T/64, B), block 256 (4 waves). Workgroup = 64 t-rows x all 512 outs.
__global__ __launch_bounds__(256, 2) void layer_fused(
    const u16* __restrict__ xin, u16* __restrict__ xout, const u16* __restrict__ Wc,
    const u16* __restrict__ Wrs, const u16* __restrict__ rsb, const u16* __restrict__ ctxt,
    u16* __restrict__ oacc, int layer, int dil, int first, int last) {
    __shared__ u16 lds[27136];  // ph1: As[64*40]@0, Bs[512*40]@2560 | ph2/3: acts[64*264]@0, Bs2[256*40]@16896
    const int tid = threadIdx.x;
    const int w = tid >> 6, lane = tid & 63, l15 = lane & 15, quad = lane >> 4;
    const int b = blockIdx.y;
    const int t0 = blockIdx.x * 64;
    const int srow = tid >> 2;       // 0..63
    const int sk = (tid & 3) * 8;    // 0,8,16,24

    const u16* xb = xin + (size_t)b * T * 256;
    const u16* cb = ctxt + (size_t)b * T * 96;
    const u16* Wl = Wc + (size_t)layer * 512 * 864;

    float4v acc[4][8];
#pragma unroll
    for (int m = 0; m < 4; m++)
#pragma unroll
        for (int j = 0; j < 8; j++) acc[m][j] = (float4v){0.f, 0.f, 0.f, 0.f};

    // ---- phase 1: a[t][out] = im2col(x; ctx; 1.0) . Wc[out][.]  (K=864, 27 steps) ----
    for (int step = 0; step < 27; step++) {
        __syncthreads();
        short8 av;
        if (step < 24) {
            int seg = step >> 3, cs = step & 7;
            int t = t0 + srow + (seg - 1) * dil;
            if (t >= 0 && t < T) av = *(const short8*)(xb + (size_t)t * 256 + cs * 32 + sk);
            else av = (short8){0, 0, 0, 0, 0, 0, 0, 0};
        } else {
            av = *(const short8*)(cb + (size_t)(t0 + srow) * 96 + (step - 24) * 32 + sk);
        }
        *(short8*)(&lds[srow * 40 + sk]) = av;
        const u16* wstep = Wl + step * 32;
#pragma unroll
        for (int r = 0; r < 8; r++) {
            int out = r * 64 + srow;
            short8 bv = *(const short8*)(wstep + (size_t)out * 864 + sk);
            *(short8*)(&lds[2560 + out * 40 + sk]) = bv;
        }
        __syncthreads();
        short8 af[4], bf[8];
#pragma unroll
        for (int m = 0; m < 4; m++)
            af[m] = *(const short8*)(&lds[(m * 16 + l15) * 40 + quad * 8]);
#pragma unroll
        for (int j = 0; j < 8; j++) {
            int nt = (j < 4) ? (4 * w + j) : (16 + 4 * w + (j - 4));
            bf[j] = *(const short8*)(&lds[2560 + (nt * 16 + l15) * 40 + quad * 8]);
        }
#pragma unroll
        for (int m = 0; m < 4; m++)
#pragma unroll
            for (int j = 0; j < 8; j++)
                acc[m][j] = __builtin_amdgcn_mfma_f32_16x16x32_bf16(af[m], bf[j], acc[m][j], 0, 0, 0);
    }

    // ---- phase 2: gated activation -> acts in LDS (bf16, [64][264]) ----
    __syncthreads();
#pragma unroll
    for (int m = 0; m < 4; m++) {
#pragma unroll
        for (int j = 0; j < 4; j++) {
            int c = 64 * w + 16 * j + l15;
#pragma unroll
            for (int r = 0; r < 4; r++) {
                int tl = m * 16 + quad * 4 + r;
                float at = acc[m][j][r], as = acc[m][j + 4][r];
                float e2 = __expf(2.f * at);
                float th = 1.f - 2.f / (e2 + 1.f);
                float sg = 1.f / (1.f + __expf(-as));
                lds[tl * 264 + c] = f2b(th * sg);
            }
        }
    }
    __syncthreads();

    // ---- phase 3: rs = acts . Wrs^T (K=256), two out-halves ----
    u16* xo = xout + (size_t)b * T * 256;
    u16* oo = oacc + (size_t)b * T * 256;
#pragma unroll 1
    for (int half = 0; half < 2; half++) {
        if (half == 1 && last) break;
        float4v acc2[4][4];
#pragma unroll
        for (int m = 0; m < 4; m++)
#pragma unroll
            for (int j = 0; j < 4; j++) acc2[m][j] = (float4v){0.f, 0.f, 0.f, 0.f};
        const u16* wl = Wrs + ((size_t)layer * 512 + half * 256) * 256;
        for (int step = 0; step < 8; step++) {
            __syncthreads();
#pragma unroll
            for (int r = 0; r < 4; r++) {
                int out = r * 64 + srow;
                short8 bv = *(const short8*)(wl + (size_t)out * 256 + step * 32 + sk);
                *(short8*)(&lds[16896 + out * 40 + sk]) = bv;
            }
            __syncthreads();
            short8 af[4], bf2[4];
#pragma unroll
            for (int m = 0; m < 4; m++)
                af[m] = *(const short8*)(&lds[(m * 16 + l15) * 264 + step * 32 + quad * 8]);
#pragma unroll
            for (int j = 0; j < 4; j++)
                bf2[j] = *(const short8*)(&lds[16896 + ((4 * w + j) * 16 + l15) * 40 + quad * 8]);
#pragma unroll
            for (int m = 0; m < 4; m++)
#pragma unroll
                for (int j = 0; j < 4; j++)
                    acc2[m][j] =
                        __builtin_amdgcn_mfma_f32_16x16x32_bf16(af[m], bf2[j], acc2[m][j], 0, 0, 0);
        }
        float bias[4];
#pragma unroll
        for (int j = 0; j < 4; j++)
            bias[j] = b2f(rsb[layer * 512 + half * 256 + 64 * w + 16 * j + l15]);
#pragma unroll
        for (int m = 0; m < 4; m++) {
#pragma unroll
            for (int j = 0; j < 4; j++) {
                int c = 64 * w + 16 * j + l15;
#pragma unroll
                for (int r = 0; r < 4; r++) {
                    int t = t0 + m * 16 + quad * 4 + r;
                    size_t idx = (size_t)t * 256 + c;
                    float v = acc2[m][j][r] + bias[j];
                    if (half == 0) {
                        if (last) oo[idx] = f2b(b2f(oo[idx]) + v);      // skip += rs[:256] (last)
                        else      xo[idx] = f2b(b2f(xb[idx]) + v);     // x_new = x_old + rs[:256]
                    } else {
                        oo[idx] = first ? f2b(v) : f2b(b2f(oo[idx]) + v);  // skip accumulate
                    }
                }
            }
        }
    }
}

// ---------------- end conv (256 -> 8) + affine + output assembly ----------------
template <bool F32>
__global__ void end_kernel(const u16* __restrict__ oacc, const void* __restrict__ w_end,
                           const void* __restrict__ b_end, const void* __restrict__ fc,
                           void* __restrict__ out, const int* __restrict__ flag) {
    if (skipv<F32>(flag)) return;
    __shared__ float wsm[2048];
    __shared__ float bsm[8];
    const int tid = threadIdx.x;
    for (int it = 0; it < 8; it++) wsm[it * 256 + tid] = LD<F32>(w_end, it * 256 + tid);
    if (tid < 8) bsm[tid] = LD<F32>(b_end, tid);
    __syncthreads();
    int gid = blockIdx.x * 256 + tid;  // 0..32767
    int b = gid >> 12, t = gid & 4095;
    float o8[8];
#pragma unroll
    for (int o = 0; o < 8; o++) o8[o] = bsm[o];
    const u16* orow = oacc + (size_t)(b * T + t) * 256;
    for (int c8 = 0; c8 < 32; c8++) {
        short8 v8 = *(const short8*)(orow + c8 * 8);
#pragma unroll
        for (int k = 0; k < 8; k++) {
            float v = b2f((u16)v8[k]);
            int c = c8 * 8 + k;
#pragma unroll
            for (int o = 0; o < 8; o++) o8[o] += wsm[o * 256 + c] * v;
        }
    }
    size_t ob8 = (size_t)b * 8 * T;
#pragma unroll
    for (int j = 0; j < 4; j++) {
        float f1v = LD<F32>(fc, ob8 + (size_t)(4 + j) * T + t);
        float ls = o8[4 + j];
        float val = __expf(ls) * f1v + o8[j];
        if constexpr (F32) {
            float* o = (float*)out;
            o[ob8 + (size_t)j * T + t] = ((const float*)fc)[ob8 + (size_t)j * T + t];
            o[ob8 + (size_t)(4 + j) * T + t] = val;
            o[(size_t)BATCH * 8 * T + ((size_t)b * 4 + j) * T + t] = ls;
        } else {
            u16* o = (u16*)out;
            o[ob8 + (size_t)j * T + t] = ((const u16*)fc)[ob8 + (size_t)j * T + t];
            o[ob8 + (size_t)(4 + j) * T + t] = f2b(val);
            o[(size_t)BATCH * 8 * T + ((size_t)b * 4 + j) * T + t] = f2b(ls);
        }
    }
}

template <bool F32>
static void launch_prep(const void* forecast, const void* context, const void* start_w,
                        const void* start_b, const void* cond_w, const void* cond_b,
                        const void* in_w, const void* in_b, const void* rs_w, const void* rs_b,
                        u16* xA, u16* ctxt, u16* Wc, u16* Wrs, u16* rsb, const int* flag,
                        hipStream_t stream) {
    cvt_kernel<F32><<<4096, 256, 0, stream>>>(rs_w, Wrs, 8 * 512 * 256, flag);
    cvt_kernel<F32><<<16, 256, 0, stream>>>(rs_b, rsb, 4096, flag);
    prep_wc<F32><<<4096, 256, 0, stream>>>(in_w, in_b, cond_w, cond_b, Wc, flag);
    prep_ctx<F32><<<dim3(64, BATCH), 256, 0, stream>>>(context, ctxt, flag);
    start_kernel<F32><<<dim3(64, BATCH), 256, 0, stream>>>(forecast, start_w, start_b, xA, flag);
}

extern "C" void kernel_launch(void* const* d_in, const int* in_sizes, int n_in,
                              void* d_out, int out_size, void* d_ws, size_t ws_size,
                              hipStream_t stream) {
    const void* forecast = d_in[0];
    const void* context  = d_in[1];
    const void* start_w  = d_in[2];
    const void* start_b  = d_in[3];
    const void* cond_w   = d_in[4];
    const void* cond_b   = d_in[5];
    const void* in_w     = d_in[6];
    const void* in_b     = d_in[7];
    const void* rs_w     = d_in[8];
    const void* rs_b     = d_in[9];
    const void* end_w    = d_in[10];
    const void* end_b    = d_in[11];

    char* W = (char*)d_ws;
    int* flag = (int*)(W + 0);
    u16* xA   = (u16*)(W + 256);                  // 16,777,216
    u16* xB   = (u16*)(W + 256 + 16777216);       // 16,777,216
    u16* oacc = (u16*)(W + 256 + 33554432);       // 16,777,216
    u16* ctxt = (u16*)(W + 256 + 50331648);       //  6,291,456
    u16* Wc   = (u16*)(W + 256 + 56623104);       //  7,077,888
    u16* Wrs  = (u16*)(W + 256 + 63700992);       //  2,097,152
    u16* rsb  = (u16*)(W + 256 + 65798144);       //      8,192  -> total ~62.8 MiB

    probe_kernel<<<1, 256, 0, stream>>>((const u16*)forecast, flag);

    launch_prep<false>(forecast, context, start_w, start_b, cond_w, cond_b, in_w, in_b, rs_w,
                       rs_b, xA, ctxt, Wc, Wrs, rsb, flag, stream);
    launch_prep<true>(forecast, context, start_w, start_b, cond_w, cond_b, in_w, in_b, rs_w,
                      rs_b, xA, ctxt, Wc, Wrs, rsb, flag, stream);

    const int dil[NLAYERS] = {1, 2, 4, 8, 16, 32, 64, 128};
    for (int l = 0; l < NLAYERS; l++) {
        const u16* xi = (l & 1) ? xB : xA;
        u16* xo = (l & 1) ? xA : xB;
        layer_fused<<<dim3(64, BATCH), 256, 0, stream>>>(xi, xo, Wc, Wrs, rsb, ctxt, oacc, l,
                                                         dil[l], l == 0, l == NLAYERS - 1);
    }

    end_kernel<false><<<128, 256, 0, stream>>>(oacc, end_w, end_b, forecast, d_out, flag);
    end_kernel<true><<<128, 256, 0, stream>>>(oacc, end_w, end_b, forecast, d_out, flag);
}

// Round 5
// 889.318 us; speedup vs baseline: 11.8421x; 1.0389x over previous
//
#include <hip/hip_runtime.h>

#define BATCH 8
#define T 4096
#define NCH 256
#define NCTX 80
#define NLAYERS 8

typedef unsigned short u16;
typedef __attribute__((ext_vector_type(8))) short short8;
typedef __attribute__((ext_vector_type(4))) short short4v;
typedef __attribute__((ext_vector_type(4))) float float4v;

__device__ __forceinline__ float b2f(u16 u) {
    unsigned v = ((unsigned)u) << 16;
    float f;
    __builtin_memcpy(&f, &v, 4);
    return f;
}
__device__ __forceinline__ u16 f2b(float f) {
    unsigned v;
    __builtin_memcpy(&v, &f, 4);
    unsigned r = v + 0x7FFFu + ((v >> 16) & 1u);
    return (u16)(r >> 16);
}

template <bool F32>
__device__ __forceinline__ float LD(const void* p, size_t i) {
    if constexpr (F32) return ((const float*)p)[i];
    else return b2f(((const u16*)p)[i]);
}
template <bool F32>
__device__ __forceinline__ bool skipv(const int* flag) {
    int f = *flag;
    return F32 ? (f != 0) : (f == 0);
}

// ---------------- dtype probe ----------------
__global__ void probe_kernel(const u16* __restrict__ fc, int* __restrict__ flag) {
    __shared__ int cnt;
    if (threadIdx.x == 0) cnt = 0;
    __syncthreads();
    int local = 0;
#pragma unroll
    for (int j = 0; j < 16; j++) {
        u16 u = fc[2 * (threadIdx.x * 16 + j)];
        int e = (u >> 7) & 0xFF;
        if (e >= 0x50 && e <= 0x85) local++;
    }
    atomicAdd(&cnt, local);
    __syncthreads();
    if (threadIdx.x == 0) *flag = (cnt >= 2048) ? 1 : 0;  // 1 = bf16 inputs
}

// ---------------- generic convert to bf16 ----------------
template <bool F32>
__global__ void cvt_kernel(const void* __restrict__ src, u16* __restrict__ dst, int n,
                           const int* __restrict__ flag) {
    if (skipv<F32>(flag)) return;
    int i = blockIdx.x * 256 + threadIdx.x;
    if (i < n) dst[i] = f2b(LD<F32>(src, i));
}

// ---------------- build Wc [8][512][864] ----------------
template <bool F32>
__global__ void prep_wc(const void* __restrict__ in_w, const void* __restrict__ in_b,
                        const void* __restrict__ cond_w, const void* __restrict__ cond_b,
                        u16* __restrict__ Wc, const int* __restrict__ flag) {
    if (skipv<F32>(flag)) return;
    int row = blockIdx.x;  // 0..4095 = l*512+o
    for (int it = 0; it < 4; it++) {
        int col = it * 256 + threadIdx.x;
        if (col >= 864) break;
        float v;
        if (col < 256)       v = LD<F32>(in_w, ((size_t)row * 256 + col) * 3);
        else if (col < 512)  v = LD<F32>(in_w, ((size_t)row * 256 + (col - 256)) * 3 + 1);
        else if (col < 768)  v = LD<F32>(in_w, ((size_t)row * 256 + (col - 512)) * 3 + 2);
        else if (col < 848)  v = LD<F32>(cond_w, (size_t)row * 80 + (col - 768));
        else if (col == 848) v = LD<F32>(in_b, row) + LD<F32>(cond_b, row);
        else                 v = 0.f;
        Wc[(size_t)row * 864 + col] = f2b(v);
    }
}

// ---------------- transpose context -> ctx_t [B][T][96] ----------------
template <bool F32>
__global__ void prep_ctx(const void* __restrict__ ctx, u16* __restrict__ ctxt,
                         const int* __restrict__ flag) {
    if (skipv<F32>(flag)) return;
    __shared__ float sm[80][65];
    const int tid = threadIdx.x;
    const int b = blockIdx.y, t0 = blockIdx.x * 64;
    for (int it = 0; it < 20; it++) {
        int e = it * 256 + tid;
        int j = e >> 6, tt = e & 63;
        sm[j][tt] = LD<F32>(ctx, ((size_t)b * 80 + j) * T + t0 + tt);
    }
    __syncthreads();
    for (int it = 0; it < 24; it++) {
        int e = it * 256 + tid;
        int r = e / 96, c = e - r * 96;
        float v = (c < 80) ? sm[c][r] : (c == 80 ? 1.f : 0.f);
        ctxt[((size_t)b * T + t0 + r) * 96 + c] = f2b(v);
    }
}

// ---------------- start conv (4 -> 256, 1x1) -> x_t [B][T][256] ----------------
template <bool F32>
__global__ void start_kernel(const void* __restrict__ fc, const void* __restrict__ w,
                             const void* __restrict__ bias, u16* __restrict__ xt,
                             const int* __restrict__ flag) {
    if (skipv<F32>(flag)) return;
    __shared__ float fsm[4][64];
    __shared__ float wsm[1024];
    __shared__ float bsm[256];
    const int tid = threadIdx.x;
    const int b = blockIdx.y, t0 = blockIdx.x * 64;
    fsm[tid >> 6][tid & 63] = LD<F32>(fc, ((size_t)b * 8 + (tid >> 6)) * T + t0 + (tid & 63));
    for (int it = 0; it < 4; it++) wsm[it * 256 + tid] = LD<F32>(w, it * 256 + tid);
    bsm[tid] = LD<F32>(bias, tid);
    __syncthreads();
    for (int r = 0; r < 64; r++) {
        int c = tid;
        float a = bsm[c];
#pragma unroll
        for (int k = 0; k < 4; k++) a += wsm[c * 4 + k] * fsm[k][r];
        xt[((size_t)b * T + t0 + r) * 256 + c] = f2b(a);
    }
}

// ---------------- fused WaveNet layer ----------------
// grid (T/64, B), block 256 (4 waves). Conflict-free strides: A/B/Bs2 rows 36 u16
// (72 B = 18-dword stride -> bank-uniform b64 access), acts rows 260 u16.
// Single-set register prefetch overlaps next-step global loads with MFMA.
__global__ __launch_bounds__(256, 2) void layer_fused(
    const u16* __restrict__ xin, u16* __restrict__ xout, const u16* __restrict__ Wc,
    const u16* __restrict__ Wrs, const u16* __restrict__ rsb, const u16* __restrict__ ctxt,
    u16* __restrict__ oacc, int layer, int dil, int first, int last) {
    // ph1: As[64*36]@0, Bs[512*36]@2304 | ph2/3: acts[64*260]@0, Bs2[256*36]@16640
    __shared__ u16 lds[25856];  // 51,712 B
    const int tid = threadIdx.x;
    const int w = tid >> 6, lane = tid & 63, l15 = lane & 15, quad = lane >> 4;
    const int b = blockIdx.y;
    const int t0 = blockIdx.x * 64;
    const int srow = tid >> 2;       // 0..63
    const int sk = (tid & 3) * 8;    // 0,8,16,24

    const u16* xb = xin + (size_t)b * T * 256;
    const u16* cb = ctxt + (size_t)b * T * 96;
    const u16* Wl = Wc + (size_t)layer * 512 * 864;

    auto ld8 = [&](int idx) -> short8 {
        short4v lo = *(const short4v*)(&lds[idx]);
        short4v hi = *(const short4v*)(&lds[idx + 4]);
        return __builtin_shufflevector(lo, hi, 0, 1, 2, 3, 4, 5, 6, 7);
    };
    auto st8 = [&](int idx, short8 v) {
        *(short4v*)(&lds[idx]) = __builtin_shufflevector(v, v, 0, 1, 2, 3);
        *(short4v*)(&lds[idx + 4]) = __builtin_shufflevector(v, v, 4, 5, 6, 7);
    };

    float4v acc[4][8];
#pragma unroll
    for (int m = 0; m < 4; m++)
#pragma unroll
        for (int j = 0; j < 8; j++) acc[m][j] = (float4v){0.f, 0.f, 0.f, 0.f};

    // ---- phase 1: a[t][out] = im2col(x; ctx; 1.0) . Wc  (K=864, 27 steps of 32) ----
    auto fetch1 = [&](int step, short8& av, short8* bv) {
        if (step < 24) {
            int seg = step >> 3, cs = step & 7;
            int t = t0 + srow + (seg - 1) * dil;
            if (t >= 0 && t < T) av = *(const short8*)(xb + (size_t)t * 256 + cs * 32 + sk);
            else av = (short8){0, 0, 0, 0, 0, 0, 0, 0};
        } else {
            av = *(const short8*)(cb + (size_t)(t0 + srow) * 96 + (step - 24) * 32 + sk);
        }
        const u16* wstep = Wl + step * 32 + sk;
#pragma unroll
        for (int r = 0; r < 8; r++)
            bv[r] = *(const short8*)(wstep + (size_t)(r * 64 + srow) * 864);
    };
    auto stage1 = [&](const short8& av, const short8* bv) {
        st8(srow * 36 + sk, av);
#pragma unroll
        for (int r = 0; r < 8; r++) st8(2304 + (r * 64 + srow) * 36 + sk, bv[r]);
    };
    auto compute1 = [&]() {
        short8 af[4], bf[8];
#pragma unroll
        for (int m = 0; m < 4; m++) af[m] = ld8((m * 16 + l15) * 36 + quad * 8);
#pragma unroll
        for (int j = 0; j < 8; j++) {
            int nt = (j < 4) ? (4 * w + j) : (16 + 4 * w + (j - 4));
            bf[j] = ld8(2304 + (nt * 16 + l15) * 36 + quad * 8);
        }
#pragma unroll
        for (int m = 0; m < 4; m++)
#pragma unroll
            for (int j = 0; j < 8; j++)
                acc[m][j] = __builtin_amdgcn_mfma_f32_16x16x32_bf16(af[m], bf[j], acc[m][j], 0, 0, 0);
    };

    {
        short8 a0, b0[8];
        fetch1(0, a0, b0);
        for (int s = 0; s < 27; s++) {
            stage1(a0, b0);
            __syncthreads();
            if (s + 1 < 27) fetch1(s + 1, a0, b0);  // overlap next loads with MFMA
            compute1();
            __syncthreads();
        }
    }

    // ---- phase 2: gated activation -> acts in LDS (bf16, stride 260) ----
#pragma unroll
    for (int m = 0; m < 4; m++) {
#pragma unroll
        for (int j = 0; j < 4; j++) {
            int c = 64 * w + 16 * j + l15;
#pragma unroll
            for (int r = 0; r < 4; r++) {
                int tl = m * 16 + quad * 4 + r;
                float at = acc[m][j][r], as = acc[m][j + 4][r];
                float e2 = __expf(2.f * at);
                float th = 1.f - 2.f / (e2 + 1.f);
                float sg = 1.f / (1.f + __expf(-as));
                lds[tl * 260 + c] = f2b(th * sg);
            }
        }
    }
    __syncthreads();

    // ---- phase 3: rs = acts . Wrs^T (K=256, 8 steps of 32), two out-halves ----
    u16* xo = xout + (size_t)b * T * 256;
    u16* oo = oacc + (size_t)b * T * 256;
    const int nhalf = last ? 1 : 2;
#pragma unroll 1
    for (int half = 0; half < nhalf; half++) {
        float4v acc2[4][4];
#pragma unroll
        for (int m = 0; m < 4; m++)
#pragma unroll
            for (int j = 0; j < 4; j++) acc2[m][j] = (float4v){0.f, 0.f, 0.f, 0.f};
        const u16* wl = Wrs + ((size_t)layer * 512 + half * 256) * 256 + sk;

        auto fetch3 = [&](int step, short8* bv) {
#pragma unroll
            for (int r = 0; r < 4; r++)
                bv[r] = *(const short8*)(wl + (size_t)(r * 64 + srow) * 256 + step * 32);
        };
        auto stage3 = [&](const short8* bv) {
#pragma unroll
            for (int r = 0; r < 4; r++) st8(16640 + (r * 64 + srow) * 36 + sk, bv[r]);
        };
        auto compute3 = [&](int step) {
            short8 af[4], bf2[4];
#pragma unroll
            for (int m = 0; m < 4; m++)
                af[m] = ld8((m * 16 + l15) * 260 + step * 32 + quad * 8);
#pragma unroll
            for (int j = 0; j < 4; j++)
                bf2[j] = ld8(16640 + ((4 * w + j) * 16 + l15) * 36 + quad * 8);
#pragma unroll
            for (int m = 0; m < 4; m++)
#pragma unroll
                for (int j = 0; j < 4; j++)
                    acc2[m][j] =
                        __builtin_amdgcn_mfma_f32_16x16x32_bf16(af[m], bf2[j], acc2[m][j], 0, 0, 0);
        };

        short8 c0[4];
        fetch3(0, c0);
        for (int s = 0; s < 8; s++) {
            stage3(c0);
            __syncthreads();
            if (s + 1 < 8) fetch3(s + 1, c0);
            compute3(s);
            __syncthreads();
        }

        float bias[4];
#pragma unroll
        for (int j = 0; j < 4; j++)
            bias[j] = b2f(rsb[layer * 512 + half * 256 + 64 * w + 16 * j + l15]);
#pragma unroll
        for (int m = 0; m < 4; m++) {
#pragma unroll
            for (int j = 0; j < 4; j++) {
                int c = 64 * w + 16 * j + l15;
#pragma unroll
                for (int r = 0; r < 4; r++) {
                    int t = t0 + m * 16 + quad * 4 + r;
                    size_t idx = (size_t)t * 256 + c;
                    float v = acc2[m][j][r] + bias[j];
                    if (half == 0) {
                        if (last) oo[idx] = f2b(b2f(oo[idx]) + v);   // skip += rs[:256] (last)
                        else      xo[idx] = f2b(b2f(xb[idx]) + v);  // x_new = x_old + rs[:256]
                    } else {
                        oo[idx] = first ? f2b(v) : f2b(b2f(oo[idx]) + v);  // skip accumulate
                    }
                }
            }
        }
    }
}

// ---------------- end conv (256 -> 8) + affine + output assembly ----------------
template <bool F32>
__global__ void end_kernel(const u16* __restrict__ oacc, const void* __restrict__ w_end,
                           const void* __restrict__ b_end, const void* __restrict__ fc,
                           void* __restrict__ out, const int* __restrict__ flag) {
    if (skipv<F32>(flag)) return;
    __shared__ float wsm[2048];
    __shared__ float bsm[8];
    const int tid = threadIdx.x;
    for (int it = 0; it < 8; it++) wsm[it * 256 + tid] = LD<F32>(w_end, it * 256 + tid);
    if (tid < 8) bsm[tid] = LD<F32>(b_end, tid);
    __syncthreads();
    int gid = blockIdx.x * 256 + tid;  // 0..32767
    int b = gid >> 12, t = gid & 4095;
    float o8[8];
#pragma unroll
    for (int o = 0; o < 8; o++) o8[o] = bsm[o];
    const u16* orow = oacc + (size_t)(b * T + t) * 256;
    for (int c8 = 0; c8 < 32; c8++) {
        short8 v8 = *(const short8*)(orow + c8 * 8);
#pragma unroll
        for (int k = 0; k < 8; k++) {
            float v = b2f((u16)v8[k]);
            int c = c8 * 8 + k;
#pragma unroll
            for (int o = 0; o < 8; o++) o8[o] += wsm[o * 256 + c] * v;
        }
    }
    size_t ob8 = (size_t)b * 8 * T;
#pragma unroll
    for (int j = 0; j < 4; j++) {
        float f1v = LD<F32>(fc, ob8 + (size_t)(4 + j) * T + t);
        float ls = o8[4 + j];
        float val = __expf(ls) * f1v + o8[j];
        if constexpr (F32) {
            float* o = (float*)out;
            o[ob8 + (size_t)j * T + t] = ((const float*)fc)[ob8 + (size_t)j * T + t];
            o[ob8 + (size_t)(4 + j) * T + t] = val;
            o[(size_t)BATCH * 8 * T + ((size_t)b * 4 + j) * T + t] = ls;
        } else {
            u16* o = (u16*)out;
            o[ob8 + (size_t)j * T + t] = ((const u16*)fc)[ob8 + (size_t)j * T + t];
            o[ob8 + (size_t)(4 + j) * T + t] = f2b(val);
            o[(size_t)BATCH * 8 * T + ((size_t)b * 4 + j) * T + t] = f2b(ls);
        }
    }
}

template <bool F32>
static void launch_prep(const void* forecast, const void* context, const void* start_w,
                        const void* start_b, const void* cond_w, const void* cond_b,
                        const void* in_w, const void* in_b, const void* rs_w, const void* rs_b,
                        u16* xA, u16* ctxt, u16* Wc, u16* Wrs, u16* rsb, const int* flag,
                        hipStream_t stream) {
    cvt_kernel<F32><<<4096, 256, 0, stream>>>(rs_w, Wrs, 8 * 512 * 256, flag);
    cvt_kernel<F32><<<16, 256, 0, stream>>>(rs_b, rsb, 4096, flag);
    prep_wc<F32><<<4096, 256, 0, stream>>>(in_w, in_b, cond_w, cond_b, Wc, flag);
    prep_ctx<F32><<<dim3(64, BATCH), 256, 0, stream>>>(context, ctxt, flag);
    start_kernel<F32><<<dim3(64, BATCH), 256, 0, stream>>>(forecast, start_w, start_b, xA, flag);
}

extern "C" void kernel_launch(void* const* d_in, const int* in_sizes, int n_in,
                              void* d_out, int out_size, void* d_ws, size_t ws_size,
                              hipStream_t stream) {
    const void* forecast = d_in[0];
    const void* context  = d_in[1];
    const void* start_w  = d_in[2];
    const void* start_b  = d_in[3];
    const void* cond_w   = d_in[4];
    const void* cond_b   = d_in[5];
    const void* in_w     = d_in[6];
    const void* in_b     = d_in[7];
    const void* rs_w     = d_in[8];
    const void* rs_b     = d_in[9];
    const void* end_w    = d_in[10];
    const void* end_b    = d_in[11];

    char* W = (char*)d_ws;
    int* flag = (int*)(W + 0);
    u16* xA   = (u16*)(W + 256);                  // 16,777,216
    u16* xB   = (u16*)(W + 256 + 16777216);       // 16,777,216
    u16* oacc = (u16*)(W + 256 + 33554432);       // 16,777,216
    u16* ctxt = (u16*)(W + 256 + 50331648);       //  6,291,456
    u16* Wc   = (u16*)(W + 256 + 56623104);       //  7,077,888
    u16* Wrs  = (u16*)(W + 256 + 63700992);       //  2,097,152
    u16* rsb  = (u16*)(W + 256 + 65798144);       //      8,192  -> total ~62.8 MiB

    probe_kernel<<<1, 256, 0, stream>>>((const u16*)forecast, flag);

    launch_prep<false>(forecast, context, start_w, start_b, cond_w, cond_b, in_w, in_b, rs_w,
                       rs_b, xA, ctxt, Wc, Wrs, rsb, flag, stream);
    launch_prep<true>(forecast, context, start_w, start_b, cond_w, cond_b, in_w, in_b, rs_w,
                      rs_b, xA, ctxt, Wc, Wrs, rsb, flag, stream);

    const int dil[NLAYERS] = {1, 2, 4, 8, 16, 32, 64, 128};
    for (int l = 0; l < NLAYERS; l++) {
        const u16* xi = (l & 1) ? xB : xA;
        u16* xo = (l & 1) ? xA : xB;
        layer_fused<<<dim3(64, BATCH), 256, 0, stream>>>(xi, xo, Wc, Wrs, rsb, ctxt, oacc, l,
                                                         dil[l], l == 0, l == NLAYERS - 1);
    }

    end_kernel<false><<<128, 256, 0, stream>>>(oacc, end_w, end_b, forecast, d_out, flag);
    end_kernel<true><<<128, 256, 0, stream>>>(oacc, end_w, end_b, forecast, d_out, flag);
}